// Round 14
// baseline (126.843 us; speedup 1.0000x reference)
//
#include <hip/hip_runtime.h>

#define HH 2048
#define WW 2048
#define NN (HH*WW)

static constexpr unsigned RANK0 = 1677721u;   // floor(0.4*(NN-1))
static constexpr unsigned KEYLO = 0xB000u;
static constexpr unsigned KEYHI_ = 0xC000u;
static constexpr int NBINS = 4096;
static constexpr int NPART = 2048;

// fused morph tile geometry: 32x128 tile, halo 6
#define TH 32
#define TW 128
#define LR 44            // TH + 12 rows (halo 6 each side)
#define LCP 148          // padded LDS row stride in floats (data cols [0,144))

struct Scal {
  unsigned keyhiA, keyhiB, rA, rB;
  double thr, c0, c1;
};

// ws layout: [bufA NN floats][zeroed ctl: coarse|under|over|midA|midB|h2A|h2B][scal][part]
static constexpr size_t OFF_CTL    = (size_t)NN * 4;
static constexpr size_t OFF_COARSE = OFF_CTL;
static constexpr size_t OFF_UNDER  = OFF_COARSE + (size_t)NBINS * 4;
static constexpr size_t OFF_OVER   = OFF_UNDER + 4;
static constexpr size_t OFF_MIDA   = OFF_OVER + 4;
static constexpr size_t OFF_MIDB   = OFF_MIDA + 1024;
static constexpr size_t OFF_H2A    = OFF_MIDB + 1024;
static constexpr size_t OFF_H2B    = OFF_H2A + 65536ull * 4;
static constexpr size_t CTL_END    = OFF_H2B + 65536ull * 4;
static constexpr size_t CTL_BYTES  = CTL_END - OFF_CTL;
static constexpr size_t OFF_SCAL   = CTL_END;                // 8-aligned
static constexpr size_t OFF_PART   = OFF_SCAL + 64;

__device__ __forceinline__ float mx3(float a, float b, float c){ return fmaxf(fmaxf(a,b),c); }
__device__ __forceinline__ float mn3(float a, float b, float c){ return fminf(fminf(a,b),c); }

__device__ __forceinline__ unsigned keyf(float x){
  unsigned b = __float_as_uint(x);
  return (b & 0x80000000u) ? ~b : (b | 0x80000000u);
}
__device__ __forceinline__ float keyinv(unsigned k){
  unsigned b = (k & 0x80000000u) ? (k ^ 0x80000000u) : ~k;
  return __uint_as_float(b);
}

// 6-float window from one LDS row: aligned b128 + two independent clamped b32
// reads (no shuffles, no branches). Clamp garbage only touches cols 0/143 which
// stay outside the pristine ring at every stage.
__device__ __forceinline__ void loadwin6(const float* __restrict__ src, int rowbase,
                                         int cL, int cC, int cR, float w[6]){
  float4 v = *reinterpret_cast<const float4*>(&src[rowbase + cC]);
  w[0] = src[rowbase + cL];
  w[1]=v.x; w[2]=v.y; w[3]=v.z; w[4]=v.w;
  w[5] = src[rowbase + cR];
}

__device__ __forceinline__ void morph4(bool DIL,
    const float pr[6], const float cr[6], const float nr[6], float w[4]){
  #pragma unroll
  for (int i = 0; i < 4; i++){
    if (DIL){
      float Ah = mx3(cr[i],   cr[i+1], cr[i+2]);
      float Av = mx3(pr[i+1], cr[i+1], nr[i+1]);
      float Ad = mx3(pr[i],   cr[i+1], nr[i+2]);
      float Aa = mx3(pr[i+2], cr[i+1], nr[i]);
      float tm = mx3(pr[i], pr[i+1], pr[i+2]);
      float bm = mx3(nr[i], nr[i+1], nr[i+2]);
      float M9 = mx3(tm, Ah, bm);
      w[i] = fmaxf(M9, 1.0f + fminf(fminf(Ah,Av), fminf(Ad,Aa)));
    } else {
      float Bh = mn3(cr[i],   cr[i+1], cr[i+2]);
      float Bv = mn3(pr[i+1], cr[i+1], nr[i+1]);
      float Bd = mn3(pr[i],   cr[i+1], nr[i+2]);
      float Ba = mn3(pr[i+2], cr[i+1], nr[i]);
      float tm = mn3(pr[i], pr[i+1], pr[i+2]);
      float bm = mn3(nr[i], nr[i+1], nr[i+2]);
      float m9 = mn3(tm, Bh, bm);
      w[i] = fminf(m9, fmaxf(fmaxf(Bh,Bv), fmaxf(Bd,Ba)) - 1.0f);
    }
  }
}

// All 6 smoothing ops (D,E,E,D,D,E) on a 32x128 tile, fully in LDS (R11
// verbatim, 52us measured), plus coarse histogram of final values.
__global__ __launch_bounds__(256)
void fused_morph_k(const float* __restrict__ in, float* __restrict__ out,
                   unsigned* __restrict__ gh, unsigned* __restrict__ under,
                   unsigned* __restrict__ over){
  __shared__ float lds[2][LR*LCP];
  const int tilec = blockIdx.x & 15;       // 16 col tiles
  const int tiler = blockIdx.x >> 4;       // 64 row tiles
  const int r0 = tiler*TH, c0 = tilec*TW;

  for (int idx = threadIdx.x; idx < LR*36; idx += 256){
    int lr = idx / 36, g = idx % 36;
    int gr = r0 - 6 + lr, gc = c0 - 8 + 4*g;
    float4 v = make_float4(0.f,0.f,0.f,0.f);
    if ((unsigned)gr < (unsigned)HH && (unsigned)gc < (unsigned)WW)
      v = *reinterpret_cast<const float4*>(in + (size_t)gr*WW + gc);
    *reinterpret_cast<float4*>(&lds[0][lr*LCP + 4*g]) = v;
  }
  __syncthreads();

  const int t = threadIdx.x;
  const int g = t % 36, s = t / 36;        // strip s covers compute rows [6s+1, 6s+7)
  const bool active = (t < 252);
  const int colC = 4*g;
  const int colL = g ? 4*g - 1 : 0;
  const int colR = (g == 35) ? 143 : 4*g + 4;
  const int gcBase = c0 - 8 + 4*g;
  const bool dilf[6] = {true,false,false,true,true,false};

  #pragma unroll 1
  for (int st = 0; st < 6; st++){
    const float* src = lds[st & 1];
    float*       dst = lds[(st & 1) ^ 1];
    if (active){
      const bool DIL = dilf[st];
      float r8[8][6];
      #pragma unroll
      for (int k = 0; k < 8; k++)
        loadwin6(src, (6*s + k)*LCP, colL, colC, colR, r8[k]);
      #pragma unroll
      for (int k = 0; k < 6; k++){
        float w[4];
        morph4(DIL, r8[k], r8[k+1], r8[k+2], w);
        int gr = r0 - 6 + 6*s + 1 + k;
        if ((unsigned)gr >= (unsigned)HH){
          w[0]=w[1]=w[2]=w[3]=0.f;
        } else {
          #pragma unroll
          for (int i = 0; i < 4; i++)
            if ((unsigned)(gcBase + i) >= (unsigned)WW) w[i] = 0.f;
        }
        *reinterpret_cast<float4*>(&dst[(6*s + 1 + k)*LCP + colC]) =
            make_float4(w[0],w[1],w[2],w[3]);
      }
    }
    __syncthreads();
  }
  // final values live in lds[0]; lds[1] is free -> coarse histogram storage
  unsigned* lh = reinterpret_cast<unsigned*>(&lds[1][0]);
  for (int i = threadIdx.x; i < NBINS; i += 256) lh[i] = 0;
  __syncthreads();

  unsigned uc = 0, oc = 0;
  for (int idx = threadIdx.x; idx < TH*(TW/4); idx += 256){
    int row = idx >> 5, gg = idx & 31;
    float4 v = *reinterpret_cast<const float4*>(&lds[0][(row+6)*LCP + 8 + 4*gg]);
    *reinterpret_cast<float4*>(out + (size_t)(r0+row)*WW + c0 + 4*gg) = v;
    float vv[4] = {v.x, v.y, v.z, v.w};
    #pragma unroll
    for (int i = 0; i < 4; i++){
      unsigned key = keyf(vv[i]);
      unsigned hi = key >> 16;
      if (hi >= KEYLO && hi < KEYHI_) atomicAdd(&lh[hi - KEYLO], 1u);
      else if (hi < KEYLO)            uc++;
      else                            oc++;
    }
  }
  __syncthreads();
  for (int i = threadIdx.x; i < NBINS; i += 256){
    unsigned c = lh[i];
    if (c) atomicAdd(&gh[i], c);
  }
  if (uc) atomicAdd(under, uc);
  if (oc) atomicAdd(over, oc);
}

__global__ void scan_coarse_k(const unsigned* __restrict__ gh, const unsigned* __restrict__ under,
                              Scal* __restrict__ sc){
  __shared__ unsigned part[256];
  __shared__ unsigned excl[256];
  int t = threadIdx.x;
  unsigned loc = 0;
  #pragma unroll
  for (int i = 0; i < NBINS/256; i++) loc += gh[t*(NBINS/256) + i];
  part[t] = loc;
  __syncthreads();
  if (t == 0){
    unsigned run = under[0];
    for (int i = 0; i < 256; i++){ excl[i] = run; run += part[i]; }
  }
  __syncthreads();
  unsigned run = excl[t];
  const unsigned r0 = RANK0, r1 = RANK0 + 1;
  #pragma unroll
  for (int i = 0; i < NBINS/256; i++){
    unsigned idx = t*(NBINS/256) + i;
    unsigned cc = gh[idx];
    if (cc){
      if (r0 >= run && r0 - run < cc){ sc->keyhiA = KEYLO + idx; sc->rA = r0 - run; }
      if (r1 >= run && r1 - run < cc){ sc->keyhiB = KEYLO + idx; sc->rB = r1 - run; }
    }
    run += cc;
  }
}

// ONE fine pass: 256-bin mid hist (LDS) + speculative 65536-bin (mid,low) 2D hist
__global__ __launch_bounds__(256)
void fine2d_k(const float* __restrict__ x, const Scal* __restrict__ sc,
              unsigned* __restrict__ midA, unsigned* __restrict__ midB,
              unsigned* __restrict__ h2A, unsigned* __restrict__ h2B){
  __shared__ unsigned hA[256], hB[256];
  hA[threadIdx.x] = 0; hB[threadIdx.x] = 0;
  __syncthreads();
  unsigned ha = sc->keyhiA, hb = sc->keyhiB;
  bool dup = (ha == hb);
  const int nItems = NN/4;
  for (int it = blockIdx.x*blockDim.x + threadIdx.x; it < nItems; it += gridDim.x*blockDim.x){
    float4 v = reinterpret_cast<const float4*>(x)[it];
    float vv[4] = {v.x, v.y, v.z, v.w};
    #pragma unroll
    for (int j = 0; j < 4; j++){
      unsigned key = keyf(vv[j]);
      unsigned hi = key >> 16;
      if (hi == ha){ atomicAdd(&hA[(key>>8)&255], 1u); atomicAdd(&h2A[key & 0xFFFFu], 1u); }
      else if (hi == hb){ atomicAdd(&hB[(key>>8)&255], 1u); atomicAdd(&h2B[key & 0xFFFFu], 1u); }
    }
  }
  __syncthreads();
  if (hA[threadIdx.x]) atomicAdd(&midA[threadIdx.x], hA[threadIdx.x]);
  if (!dup && hB[threadIdx.x]) atomicAdd(&midB[threadIdx.x], hB[threadIdx.x]);
}

// resolve mid byte (from midA/midB) then low byte (from the matching h2 row) -> thr
__global__ void scan_ml_k(const unsigned* __restrict__ midA, const unsigned* __restrict__ midB,
                          const unsigned* __restrict__ h2A, const unsigned* __restrict__ h2B,
                          Scal* __restrict__ sc){
  __shared__ unsigned h[256], excl[256];
  __shared__ unsigned res[6];   // mA, rA2, mB, rB2, lowA, lowB
  int t = threadIdx.x;
  unsigned ha = sc->keyhiA, hb = sc->keyhiB;
  bool dupHi = (ha == hb);
  unsigned rA = sc->rA, rB = sc->rB;

  h[t] = midA[t];
  __syncthreads();
  if (t == 0){ unsigned run = 0; for (int i = 0; i < 256; i++){ excl[i] = run; run += h[i]; } }
  __syncthreads();
  if (rA >= excl[t] && rA - excl[t] < h[t]){ res[0] = (unsigned)t; res[1] = rA - excl[t]; }
  if (dupHi && rB >= excl[t] && rB - excl[t] < h[t]){ res[2] = (unsigned)t; res[3] = rB - excl[t]; }
  __syncthreads();
  if (!dupHi){
    h[t] = midB[t];
    __syncthreads();
    if (t == 0){ unsigned run = 0; for (int i = 0; i < 256; i++){ excl[i] = run; run += h[i]; } }
    __syncthreads();
    if (rB >= excl[t] && rB - excl[t] < h[t]){ res[2] = (unsigned)t; res[3] = rB - excl[t]; }
    __syncthreads();
  }
  unsigned mA = res[0], rA2 = res[1], mB = res[2], rB2 = res[3];
  bool dupMid = dupHi && (mA == mB);

  h[t] = h2A[mA*256 + t];
  __syncthreads();
  if (t == 0){ unsigned run = 0; for (int i = 0; i < 256; i++){ excl[i] = run; run += h[i]; } }
  __syncthreads();
  if (rA2 >= excl[t] && rA2 - excl[t] < h[t]) res[4] = (unsigned)t;
  if (dupMid && rB2 >= excl[t] && rB2 - excl[t] < h[t]) res[5] = (unsigned)t;
  __syncthreads();
  if (!dupMid){
    const unsigned* srcH = dupHi ? h2A : h2B;
    h[t] = srcH[mB*256 + t];
    __syncthreads();
    if (t == 0){ unsigned run = 0; for (int i = 0; i < 256; i++){ excl[i] = run; run += h[i]; } }
    __syncthreads();
    if (rB2 >= excl[t] && rB2 - excl[t] < h[t]) res[5] = (unsigned)t;
    __syncthreads();
  }
  if (t == 0){
    unsigned ka = (ha << 16) | (mA << 8) | res[4];
    unsigned kb = (hb << 16) | (mB << 8) | res[5];
    double va = (double)keyinv(ka), vb = (double)keyinv(kb);
    const double FRAC = 0.4*(double)(NN-1) - (double)RANK0;   // np's gamma
    sc->thr = va + (vb - va) * FRAC;
  }
}

// load cols q-1..q+4 of `row` with zero padding (rows and cols)
__device__ __forceinline__ void load6(const float* __restrict__ p, int row, int q, float r[6]){
  if (row < 0 || row >= HH){
    r[0]=r[1]=r[2]=r[3]=r[4]=r[5]=0.f;
    return;
  }
  const float* rp = p + (size_t)row * WW;
  float4 cc = *reinterpret_cast<const float4*>(rp + q);
  r[0] = (q > 0) ? rp[q-1] : 0.f;
  r[1]=cc.x; r[2]=cc.y; r[3]=cc.z; r[4]=cc.w;
  r[5] = (q+4 < WW) ? rp[q+4] : 0.f;
}

// balloon step: aux = 1 + M9(x) computed inline; xb = (origin > thr) ? aux : x.
// f64 partial sums of origin, xb, origin*xb per block.
__global__ __launch_bounds__(256)
void balloon_k(const float* __restrict__ x, const float* __restrict__ orig,
               float* __restrict__ xb, const Scal* __restrict__ sc, double* __restrict__ part){
  double thr = sc->thr;
  double s0 = 0.0, s1 = 0.0, s2 = 0.0;   // So, Sx, Sox
  const int nItems = NN/4;
  for (int it = blockIdx.x*blockDim.x + threadIdx.x; it < nItems; it += gridDim.x*blockDim.x){
    int i = it >> 9;
    int q = (it & 511) << 2;
    float a[6], b[6], c[6];
    load6(x, i-1, q, a);
    load6(x, i,   q, b);
    load6(x, i+1, q, c);
    float4 og = *reinterpret_cast<const float4*>(orig + (size_t)i*WW + q);
    float ov[4] = {og.x, og.y, og.z, og.w};
    float r[4];
    #pragma unroll
    for (int t = 0; t < 4; t++){
      float M9 = mx3(mx3(a[t],a[t+1],a[t+2]), mx3(b[t],b[t+1],b[t+2]), mx3(c[t],c[t+1],c[t+2]));
      float aux = 1.0f + M9;
      float nx = ((double)ov[t] > thr) ? aux : b[t+1];
      r[t] = nx;
      s0 += (double)ov[t];
      s1 += (double)nx;
      s2 += (double)ov[t] * (double)nx;
    }
    *reinterpret_cast<float4*>(xb + (size_t)i*WW + q) = make_float4(r[0],r[1],r[2],r[3]);
  }
  for (int off = 32; off > 0; off >>= 1){
    s0 += __shfl_down(s0, off);
    s1 += __shfl_down(s1, off);
    s2 += __shfl_down(s2, off);
  }
  __shared__ double red[4][3];
  int lane = threadIdx.x & 63, wv = threadIdx.x >> 6;
  if (lane == 0){ red[wv][0] = s0; red[wv][1] = s1; red[wv][2] = s2; }
  __syncthreads();
  if (threadIdx.x == 0){
    part[blockIdx.x*3+0] = red[0][0]+red[1][0]+red[2][0]+red[3][0];
    part[blockIdx.x*3+1] = red[0][1]+red[1][1]+red[2][1]+red[3][1];
    part[blockIdx.x*3+2] = red[0][2]+red[1][2]+red[2][2]+red[3][2];
  }
}

__global__ void c0c1_k(const double* __restrict__ part, Scal* __restrict__ sc){
  int t = threadIdx.x;
  double s0 = 0, s1 = 0, s2 = 0;
  for (int b = t; b < NPART; b += 256){
    s0 += part[b*3+0]; s1 += part[b*3+1]; s2 += part[b*3+2];
  }
  for (int off = 32; off > 0; off >>= 1){
    s0 += __shfl_down(s0, off);
    s1 += __shfl_down(s1, off);
    s2 += __shfl_down(s2, off);
  }
  __shared__ double red[4][3];
  int lane = t & 63, wv = t >> 6;
  if (lane == 0){ red[wv][0] = s0; red[wv][1] = s1; red[wv][2] = s2; }
  __syncthreads();
  if (t == 0){
    double So = red[0][0]+red[1][0]+red[2][0]+red[3][0];
    double Sx = red[0][1]+red[1][1]+red[2][1]+red[3][1];
    double Sox= red[0][2]+red[1][2]+red[2][2]+red[3][2];
    sc->c0 = (So - Sox) / ((double)NN - Sx + 1e-8);
    sc->c1 = Sox / (Sx + 1e-8);
  }
}

// final: elementwise Chan-Vese from origin + stored xb
__global__ __launch_bounds__(256)
void final_k(const float* __restrict__ orig, const float* __restrict__ xb,
             const Scal* __restrict__ sc, float* __restrict__ out){
  double c0 = sc->c0, c1 = sc->c1;
  const int nItems = NN/4;
  for (int it = blockIdx.x*blockDim.x + threadIdx.x; it < nItems; it += gridDim.x*blockDim.x){
    float4 og = reinterpret_cast<const float4*>(orig)[it];
    float4 xv = reinterpret_cast<const float4*>(xb)[it];
    float ov[4] = {og.x, og.y, og.z, og.w};
    float xx[4] = {xv.x, xv.y, xv.z, xv.w};
    float r[4];
    #pragma unroll
    for (int t = 0; t < 4; t++){
      double o = (double)ov[t];
      double d1 = o - c1, d0 = o - c0;
      double cv = d1*d1 - d0*d0;
      r[t] = (cv < 0.0) ? 1.0f : ((cv > 0.0) ? 0.0f : xx[t]);
    }
    reinterpret_cast<float4*>(out)[it] = make_float4(r[0],r[1],r[2],r[3]);
  }
}

extern "C" void kernel_launch(void* const* d_in, const int* in_sizes, int n_in,
                              void* d_out, int out_size, void* d_ws, size_t ws_size,
                              hipStream_t stream) {
  const float* input  = (const float*)d_in[0];
  const float* origin = (const float*)d_in[1];
  float* out = (float*)d_out;

  char* ws = (char*)d_ws;
  float*    bufA   = (float*)ws;
  unsigned* coarse = (unsigned*)(ws + OFF_COARSE);
  unsigned* under  = (unsigned*)(ws + OFF_UNDER);
  unsigned* over   = (unsigned*)(ws + OFF_OVER);
  unsigned* midA   = (unsigned*)(ws + OFF_MIDA);
  unsigned* midB   = (unsigned*)(ws + OFF_MIDB);
  unsigned* h2A    = (unsigned*)(ws + OFF_H2A);
  unsigned* h2B    = (unsigned*)(ws + OFF_H2B);
  Scal*     scal   = (Scal*)(ws + OFF_SCAL);
  double*   part   = (double*)(ws + OFF_PART);

  hipMemsetAsync(ws + OFF_CTL, 0, CTL_BYTES, stream);

  // all 6 smoothing ops + coarse hist in one tiled kernel; x_final -> d_out
  fused_morph_k<<<(HH/TH)*(WW/TW), 256, 0, stream>>>(input, out, coarse, under, over);

  scan_coarse_k<<<1, 256, 0, stream>>>(coarse, under, scal);
  fine2d_k<<<2048, 256, 0, stream>>>(out, scal, midA, midB, h2A, h2B);
  scan_ml_k<<<1, 256, 0, stream>>>(midA, midB, h2A, h2B, scal);

  balloon_k<<<NPART, 256, 0, stream>>>(out, origin, bufA, scal, part);   // xb in bufA
  c0c1_k<<<1, 256, 0, stream>>>(part, scal);
  final_k<<<2048, 256, 0, stream>>>(origin, bufA, scal, out);
}

// Round 15
// 116.713 us; speedup vs baseline: 1.0868x; 1.0868x over previous
//
#include <hip/hip_runtime.h>

#define HH 2048
#define WW 2048
#define NN (HH*WW)

static constexpr unsigned RANK0 = 1677721u;   // floor(0.4*(NN-1))
static constexpr unsigned KEYLO = 0xB000u;
static constexpr unsigned KEYHI_ = 0xC000u;
static constexpr int NBINS = 4096;
static constexpr int NPART = 512;

// fused morph tile geometry: 32x128 tile, halo 6
#define TH 32
#define TW 128
#define LR 44            // TH + 12 rows (halo 6 each side)
#define LCP 148          // padded LDS row stride in floats (data cols [0,144))

struct Scal {
  unsigned keyhiA, keyhiB, rA, rB;
  double thr, c0, c1;
};

// ws layout: [bufA NN floats][zeroed ctl: coarse|under|over|midA|midB|h2A|h2B][scal][part]
static constexpr size_t OFF_CTL    = (size_t)NN * 4;
static constexpr size_t OFF_COARSE = OFF_CTL;
static constexpr size_t OFF_UNDER  = OFF_COARSE + (size_t)NBINS * 4;
static constexpr size_t OFF_OVER   = OFF_UNDER + 4;
static constexpr size_t OFF_MIDA   = OFF_OVER + 4;
static constexpr size_t OFF_MIDB   = OFF_MIDA + 1024;
static constexpr size_t OFF_H2A    = OFF_MIDB + 1024;
static constexpr size_t OFF_H2B    = OFF_H2A + 65536ull * 4;
static constexpr size_t CTL_END    = OFF_H2B + 65536ull * 4;
static constexpr size_t CTL_BYTES  = CTL_END - OFF_CTL;
static constexpr size_t OFF_SCAL   = CTL_END;                // 8-aligned
static constexpr size_t OFF_PART   = OFF_SCAL + 64;

__device__ __forceinline__ float mx3(float a, float b, float c){ return fmaxf(fmaxf(a,b),c); }
__device__ __forceinline__ float mn3(float a, float b, float c){ return fminf(fminf(a,b),c); }

__device__ __forceinline__ unsigned keyf(float x){
  unsigned b = __float_as_uint(x);
  return (b & 0x80000000u) ? ~b : (b | 0x80000000u);
}
__device__ __forceinline__ float keyinv(unsigned k){
  unsigned b = (k & 0x80000000u) ? (k ^ 0x80000000u) : ~k;
  return __uint_as_float(b);
}

// 6-float window from one LDS row via THREE aligned float4 reads (groups
// gL,g,gR; neighbors' .w/.x give the edge cols). All reads 16B-aligned,
// stride-16B across lanes -> bank-conflict-free (vs the old stride-4 b32
// edge reads at 4g+/-1 which were ~4.5-way conflicted). Clamp at g=0/35 puts
// garbage only in halo cols 0/143, outside the valid ring at every stage.
__device__ __forceinline__ void loadwin3q(const float* __restrict__ src, int rowbase,
                                          int gL, int gC, int gR, float w[6]){
  float4 vp = *reinterpret_cast<const float4*>(&src[rowbase + 4*gL]);
  float4 v  = *reinterpret_cast<const float4*>(&src[rowbase + 4*gC]);
  float4 vn = *reinterpret_cast<const float4*>(&src[rowbase + 4*gR]);
  w[0] = vp.w;
  w[1]=v.x; w[2]=v.y; w[3]=v.z; w[4]=v.w;
  w[5] = vn.x;
}

__device__ __forceinline__ void morph4(bool DIL,
    const float pr[6], const float cr[6], const float nr[6], float w[4]){
  #pragma unroll
  for (int i = 0; i < 4; i++){
    if (DIL){
      float Ah = mx3(cr[i],   cr[i+1], cr[i+2]);
      float Av = mx3(pr[i+1], cr[i+1], nr[i+1]);
      float Ad = mx3(pr[i],   cr[i+1], nr[i+2]);
      float Aa = mx3(pr[i+2], cr[i+1], nr[i]);
      float tm = mx3(pr[i], pr[i+1], pr[i+2]);
      float bm = mx3(nr[i], nr[i+1], nr[i+2]);
      float M9 = mx3(tm, Ah, bm);
      w[i] = fmaxf(M9, 1.0f + fminf(fminf(Ah,Av), fminf(Ad,Aa)));
    } else {
      float Bh = mn3(cr[i],   cr[i+1], cr[i+2]);
      float Bv = mn3(pr[i+1], cr[i+1], nr[i+1]);
      float Bd = mn3(pr[i],   cr[i+1], nr[i+2]);
      float Ba = mn3(pr[i+2], cr[i+1], nr[i]);
      float tm = mn3(pr[i], pr[i+1], pr[i+2]);
      float bm = mn3(nr[i], nr[i+1], nr[i+2]);
      float m9 = mn3(tm, Bh, bm);
      w[i] = fminf(m9, fmaxf(fmaxf(Bh,Bv), fmaxf(Bd,Ba)) - 1.0f);
    }
  }
}

// All 6 smoothing ops (D,E,E,D,D,E) on a 32x128 tile, fully in LDS (R11 ILP
// structure, conflict-free edge reads), plus coarse histogram of final values.
__global__ __launch_bounds__(256)
void fused_morph_k(const float* __restrict__ in, float* __restrict__ out,
                   unsigned* __restrict__ gh, unsigned* __restrict__ under,
                   unsigned* __restrict__ over){
  __shared__ float lds[2][LR*LCP];
  const int tilec = blockIdx.x & 15;       // 16 col tiles
  const int tiler = blockIdx.x >> 4;       // 64 row tiles
  const int r0 = tiler*TH, c0 = tilec*TW;

  for (int idx = threadIdx.x; idx < LR*36; idx += 256){
    int lr = idx / 36, g = idx % 36;
    int gr = r0 - 6 + lr, gc = c0 - 8 + 4*g;
    float4 v = make_float4(0.f,0.f,0.f,0.f);
    if ((unsigned)gr < (unsigned)HH && (unsigned)gc < (unsigned)WW)
      v = *reinterpret_cast<const float4*>(in + (size_t)gr*WW + gc);
    *reinterpret_cast<float4*>(&lds[0][lr*LCP + 4*g]) = v;
  }
  __syncthreads();

  const int t = threadIdx.x;
  const int g = t % 36, s = t / 36;        // strip s covers compute rows [6s+1, 6s+7)
  const bool active = (t < 252);
  const int gL = g ? g - 1 : 0;
  const int gR = (g == 35) ? 35 : g + 1;
  const int gcBase = c0 - 8 + 4*g;
  const bool dilf[6] = {true,false,false,true,true,false};

  #pragma unroll 1
  for (int st = 0; st < 6; st++){
    const float* src = lds[st & 1];
    float*       dst = lds[(st & 1) ^ 1];
    if (active){
      const bool DIL = dilf[st];
      float r8[8][6];
      #pragma unroll
      for (int k = 0; k < 8; k++)
        loadwin3q(src, (6*s + k)*LCP, gL, g, gR, r8[k]);
      #pragma unroll
      for (int k = 0; k < 6; k++){
        float w[4];
        morph4(DIL, r8[k], r8[k+1], r8[k+2], w);
        int gr = r0 - 6 + 6*s + 1 + k;
        if ((unsigned)gr >= (unsigned)HH){
          w[0]=w[1]=w[2]=w[3]=0.f;
        } else {
          #pragma unroll
          for (int i = 0; i < 4; i++)
            if ((unsigned)(gcBase + i) >= (unsigned)WW) w[i] = 0.f;
        }
        *reinterpret_cast<float4*>(&dst[(6*s + 1 + k)*LCP + 4*g]) =
            make_float4(w[0],w[1],w[2],w[3]);
      }
    }
    __syncthreads();
  }
  // final values live in lds[0]; lds[1] is free -> coarse histogram storage
  unsigned* lh = reinterpret_cast<unsigned*>(&lds[1][0]);
  for (int i = threadIdx.x; i < NBINS; i += 256) lh[i] = 0;
  __syncthreads();

  unsigned uc = 0, oc = 0;
  for (int idx = threadIdx.x; idx < TH*(TW/4); idx += 256){
    int row = idx >> 5, gg = idx & 31;
    float4 v = *reinterpret_cast<const float4*>(&lds[0][(row+6)*LCP + 8 + 4*gg]);
    *reinterpret_cast<float4*>(out + (size_t)(r0+row)*WW + c0 + 4*gg) = v;
    float vv[4] = {v.x, v.y, v.z, v.w};
    #pragma unroll
    for (int i = 0; i < 4; i++){
      unsigned key = keyf(vv[i]);
      unsigned hi = key >> 16;
      if (hi >= KEYLO && hi < KEYHI_) atomicAdd(&lh[hi - KEYLO], 1u);
      else if (hi < KEYLO)            uc++;
      else                            oc++;
    }
  }
  __syncthreads();
  for (int i = threadIdx.x; i < NBINS; i += 256){
    unsigned c = lh[i];
    if (c) atomicAdd(&gh[i], c);
  }
  if (uc) atomicAdd(under, uc);
  if (oc) atomicAdd(over, oc);
}

__global__ void scan_coarse_k(const unsigned* __restrict__ gh, const unsigned* __restrict__ under,
                              Scal* __restrict__ sc){
  __shared__ unsigned part[256];
  __shared__ unsigned excl[256];
  int t = threadIdx.x;
  unsigned loc = 0;
  #pragma unroll
  for (int i = 0; i < NBINS/256; i++) loc += gh[t*(NBINS/256) + i];
  part[t] = loc;
  __syncthreads();
  if (t == 0){
    unsigned run = under[0];
    for (int i = 0; i < 256; i++){ excl[i] = run; run += part[i]; }
  }
  __syncthreads();
  unsigned run = excl[t];
  const unsigned r0 = RANK0, r1 = RANK0 + 1;
  #pragma unroll
  for (int i = 0; i < NBINS/256; i++){
    unsigned idx = t*(NBINS/256) + i;
    unsigned cc = gh[idx];
    if (cc){
      if (r0 >= run && r0 - run < cc){ sc->keyhiA = KEYLO + idx; sc->rA = r0 - run; }
      if (r1 >= run && r1 - run < cc){ sc->keyhiB = KEYLO + idx; sc->rB = r1 - run; }
    }
    run += cc;
  }
}

// ONE fine pass: 256-bin mid hist (LDS) + speculative 65536-bin (mid,low) 2D hist
__global__ __launch_bounds__(256)
void fine2d_k(const float* __restrict__ x, const Scal* __restrict__ sc,
              unsigned* __restrict__ midA, unsigned* __restrict__ midB,
              unsigned* __restrict__ h2A, unsigned* __restrict__ h2B){
  __shared__ unsigned hA[256], hB[256];
  hA[threadIdx.x] = 0; hB[threadIdx.x] = 0;
  __syncthreads();
  unsigned ha = sc->keyhiA, hb = sc->keyhiB;
  bool dup = (ha == hb);
  const int nItems = NN/4;
  for (int it = blockIdx.x*blockDim.x + threadIdx.x; it < nItems; it += gridDim.x*blockDim.x){
    float4 v = reinterpret_cast<const float4*>(x)[it];
    float vv[4] = {v.x, v.y, v.z, v.w};
    #pragma unroll
    for (int j = 0; j < 4; j++){
      unsigned key = keyf(vv[j]);
      unsigned hi = key >> 16;
      if (hi == ha){ atomicAdd(&hA[(key>>8)&255], 1u); atomicAdd(&h2A[key & 0xFFFFu], 1u); }
      else if (hi == hb){ atomicAdd(&hB[(key>>8)&255], 1u); atomicAdd(&h2B[key & 0xFFFFu], 1u); }
    }
  }
  __syncthreads();
  if (hA[threadIdx.x]) atomicAdd(&midA[threadIdx.x], hA[threadIdx.x]);
  if (!dup && hB[threadIdx.x]) atomicAdd(&midB[threadIdx.x], hB[threadIdx.x]);
}

// resolve mid byte (from midA/midB) then low byte (from the matching h2 row) -> thr
__global__ void scan_ml_k(const unsigned* __restrict__ midA, const unsigned* __restrict__ midB,
                          const unsigned* __restrict__ h2A, const unsigned* __restrict__ h2B,
                          Scal* __restrict__ sc){
  __shared__ unsigned h[256], excl[256];
  __shared__ unsigned res[6];   // mA, rA2, mB, rB2, lowA, lowB
  int t = threadIdx.x;
  unsigned ha = sc->keyhiA, hb = sc->keyhiB;
  bool dupHi = (ha == hb);
  unsigned rA = sc->rA, rB = sc->rB;

  h[t] = midA[t];
  __syncthreads();
  if (t == 0){ unsigned run = 0; for (int i = 0; i < 256; i++){ excl[i] = run; run += h[i]; } }
  __syncthreads();
  if (rA >= excl[t] && rA - excl[t] < h[t]){ res[0] = (unsigned)t; res[1] = rA - excl[t]; }
  if (dupHi && rB >= excl[t] && rB - excl[t] < h[t]){ res[2] = (unsigned)t; res[3] = rB - excl[t]; }
  __syncthreads();
  if (!dupHi){
    h[t] = midB[t];
    __syncthreads();
    if (t == 0){ unsigned run = 0; for (int i = 0; i < 256; i++){ excl[i] = run; run += h[i]; } }
    __syncthreads();
    if (rB >= excl[t] && rB - excl[t] < h[t]){ res[2] = (unsigned)t; res[3] = rB - excl[t]; }
    __syncthreads();
  }
  unsigned mA = res[0], rA2 = res[1], mB = res[2], rB2 = res[3];
  bool dupMid = dupHi && (mA == mB);

  h[t] = h2A[mA*256 + t];
  __syncthreads();
  if (t == 0){ unsigned run = 0; for (int i = 0; i < 256; i++){ excl[i] = run; run += h[i]; } }
  __syncthreads();
  if (rA2 >= excl[t] && rA2 - excl[t] < h[t]) res[4] = (unsigned)t;
  if (dupMid && rB2 >= excl[t] && rB2 - excl[t] < h[t]) res[5] = (unsigned)t;
  __syncthreads();
  if (!dupMid){
    const unsigned* srcH = dupHi ? h2A : h2B;
    h[t] = srcH[mB*256 + t];
    __syncthreads();
    if (t == 0){ unsigned run = 0; for (int i = 0; i < 256; i++){ excl[i] = run; run += h[i]; } }
    __syncthreads();
    if (rB2 >= excl[t] && rB2 - excl[t] < h[t]) res[5] = (unsigned)t;
    __syncthreads();
  }
  if (t == 0){
    unsigned ka = (ha << 16) | (mA << 8) | res[4];
    unsigned kb = (hb << 16) | (mB << 8) | res[5];
    double va = (double)keyinv(ka), vb = (double)keyinv(kb);
    const double FRAC = 0.4*(double)(NN-1) - (double)RANK0;   // np's gamma
    sc->thr = va + (vb - va) * FRAC;
  }
}

// load cols q-1..q+4 of `row` with zero padding (rows and cols)
__device__ __forceinline__ void load6(const float* __restrict__ p, int row, int q, float r[6]){
  if (row < 0 || row >= HH){
    r[0]=r[1]=r[2]=r[3]=r[4]=r[5]=0.f;
    return;
  }
  const float* rp = p + (size_t)row * WW;
  float4 cc = *reinterpret_cast<const float4*>(rp + q);
  r[0] = (q > 0) ? rp[q-1] : 0.f;
  r[1]=cc.x; r[2]=cc.y; r[3]=cc.z; r[4]=cc.w;
  r[5] = (q+4 < WW) ? rp[q+4] : 0.f;
}

// balloon step: aux = 1 + M9(x) computed inline; xb = (origin > thr) ? aux : x.
// f64 partial sums of origin, xb, origin*xb per block.
__global__ __launch_bounds__(256)
void balloon_k(const float* __restrict__ x, const float* __restrict__ orig,
               float* __restrict__ xb, const Scal* __restrict__ sc, double* __restrict__ part){
  double thr = sc->thr;
  double s0 = 0.0, s1 = 0.0, s2 = 0.0;   // So, Sx, Sox
  const int nItems = NN/4;
  for (int it = blockIdx.x*blockDim.x + threadIdx.x; it < nItems; it += gridDim.x*blockDim.x){
    int i = it >> 9;
    int q = (it & 511) << 2;
    float a[6], b[6], c[6];
    load6(x, i-1, q, a);
    load6(x, i,   q, b);
    load6(x, i+1, q, c);
    float4 og = *reinterpret_cast<const float4*>(orig + (size_t)i*WW + q);
    float ov[4] = {og.x, og.y, og.z, og.w};
    float r[4];
    #pragma unroll
    for (int t = 0; t < 4; t++){
      float M9 = mx3(mx3(a[t],a[t+1],a[t+2]), mx3(b[t],b[t+1],b[t+2]), mx3(c[t],c[t+1],c[t+2]));
      float aux = 1.0f + M9;
      float nx = ((double)ov[t] > thr) ? aux : b[t+1];
      r[t] = nx;
      s0 += (double)ov[t];
      s1 += (double)nx;
      s2 += (double)ov[t] * (double)nx;
    }
    *reinterpret_cast<float4*>(xb + (size_t)i*WW + q) = make_float4(r[0],r[1],r[2],r[3]);
  }
  for (int off = 32; off > 0; off >>= 1){
    s0 += __shfl_down(s0, off);
    s1 += __shfl_down(s1, off);
    s2 += __shfl_down(s2, off);
  }
  __shared__ double red[4][3];
  int lane = threadIdx.x & 63, wv = threadIdx.x >> 6;
  if (lane == 0){ red[wv][0] = s0; red[wv][1] = s1; red[wv][2] = s2; }
  __syncthreads();
  if (threadIdx.x == 0){
    part[blockIdx.x*3+0] = red[0][0]+red[1][0]+red[2][0]+red[3][0];
    part[blockIdx.x*3+1] = red[0][1]+red[1][1]+red[2][1]+red[3][1];
    part[blockIdx.x*3+2] = red[0][2]+red[1][2]+red[2][2]+red[3][2];
  }
}

__global__ void c0c1_k(const double* __restrict__ part, Scal* __restrict__ sc){
  int t = threadIdx.x;
  double s0 = 0, s1 = 0, s2 = 0;
  for (int b = t; b < NPART; b += 256){
    s0 += part[b*3+0]; s1 += part[b*3+1]; s2 += part[b*3+2];
  }
  for (int off = 32; off > 0; off >>= 1){
    s0 += __shfl_down(s0, off);
    s1 += __shfl_down(s1, off);
    s2 += __shfl_down(s2, off);
  }
  __shared__ double red[4][3];
  int lane = t & 63, wv = t >> 6;
  if (lane == 0){ red[wv][0] = s0; red[wv][1] = s1; red[wv][2] = s2; }
  __syncthreads();
  if (t == 0){
    double So = red[0][0]+red[1][0]+red[2][0]+red[3][0];
    double Sx = red[0][1]+red[1][1]+red[2][1]+red[3][1];
    double Sox= red[0][2]+red[1][2]+red[2][2]+red[3][2];
    sc->c0 = (So - Sox) / ((double)NN - Sx + 1e-8);
    sc->c1 = Sox / (Sx + 1e-8);
  }
}

// final: elementwise Chan-Vese from origin + stored xb
__global__ __launch_bounds__(256)
void final_k(const float* __restrict__ orig, const float* __restrict__ xb,
             const Scal* __restrict__ sc, float* __restrict__ out){
  double c0 = sc->c0, c1 = sc->c1;
  const int nItems = NN/4;
  for (int it = blockIdx.x*blockDim.x + threadIdx.x; it < nItems; it += gridDim.x*blockDim.x){
    float4 og = reinterpret_cast<const float4*>(orig)[it];
    float4 xv = reinterpret_cast<const float4*>(xb)[it];
    float ov[4] = {og.x, og.y, og.z, og.w};
    float xx[4] = {xv.x, xv.y, xv.z, xv.w};
    float r[4];
    #pragma unroll
    for (int t = 0; t < 4; t++){
      double o = (double)ov[t];
      double d1 = o - c1, d0 = o - c0;
      double cv = d1*d1 - d0*d0;
      r[t] = (cv < 0.0) ? 1.0f : ((cv > 0.0) ? 0.0f : xx[t]);
    }
    reinterpret_cast<float4*>(out)[it] = make_float4(r[0],r[1],r[2],r[3]);
  }
}

extern "C" void kernel_launch(void* const* d_in, const int* in_sizes, int n_in,
                              void* d_out, int out_size, void* d_ws, size_t ws_size,
                              hipStream_t stream) {
  const float* input  = (const float*)d_in[0];
  const float* origin = (const float*)d_in[1];
  float* out = (float*)d_out;

  char* ws = (char*)d_ws;
  float*    bufA   = (float*)ws;
  unsigned* coarse = (unsigned*)(ws + OFF_COARSE);
  unsigned* under  = (unsigned*)(ws + OFF_UNDER);
  unsigned* over   = (unsigned*)(ws + OFF_OVER);
  unsigned* midA   = (unsigned*)(ws + OFF_MIDA);
  unsigned* midB   = (unsigned*)(ws + OFF_MIDB);
  unsigned* h2A    = (unsigned*)(ws + OFF_H2A);
  unsigned* h2B    = (unsigned*)(ws + OFF_H2B);
  Scal*     scal   = (Scal*)(ws + OFF_SCAL);
  double*   part   = (double*)(ws + OFF_PART);

  hipMemsetAsync(ws + OFF_CTL, 0, CTL_BYTES, stream);

  // all 6 smoothing ops + coarse hist in one tiled kernel; x_final -> d_out
  fused_morph_k<<<(HH/TH)*(WW/TW), 256, 0, stream>>>(input, out, coarse, under, over);

  scan_coarse_k<<<1, 256, 0, stream>>>(coarse, under, scal);
  fine2d_k<<<1024, 256, 0, stream>>>(out, scal, midA, midB, h2A, h2B);
  scan_ml_k<<<1, 256, 0, stream>>>(midA, midB, h2A, h2B, scal);

  balloon_k<<<NPART, 256, 0, stream>>>(out, origin, bufA, scal, part);   // xb in bufA
  c0c1_k<<<1, 256, 0, stream>>>(part, scal);
  final_k<<<2048, 256, 0, stream>>>(origin, bufA, scal, out);
}

// Round 16
// 112.620 us; speedup vs baseline: 1.1263x; 1.0363x over previous
//
#include <hip/hip_runtime.h>

#define HH 2048
#define WW 2048
#define NN (HH*WW)

static constexpr unsigned RANK0 = 1677721u;   // floor(0.4*(NN-1))
static constexpr unsigned KEYLO = 0xB000u;
static constexpr unsigned KEYHI_ = 0xC000u;
static constexpr int NBINS = 4096;
static constexpr int NPART = 512;

// fused morph tile geometry: 32x128 tile, halo 6
#define TH 32
#define TW 128
#define LR 44            // TH + 12 rows (halo 6 each side)
#define LCP 148          // padded LDS row stride in floats (data cols [0,144))

struct Scal {
  double c0, c1;
};

// ws layout: [bufA NN floats][zeroed ctl: coarse|under|over|midA|midB|h2A|h2B][scal][part]
static constexpr size_t OFF_CTL    = (size_t)NN * 4;
static constexpr size_t OFF_COARSE = OFF_CTL;
static constexpr size_t OFF_UNDER  = OFF_COARSE + (size_t)NBINS * 4;
static constexpr size_t OFF_OVER   = OFF_UNDER + 4;
static constexpr size_t OFF_MIDA   = OFF_OVER + 4;
static constexpr size_t OFF_MIDB   = OFF_MIDA + 1024;
static constexpr size_t OFF_H2A    = OFF_MIDB + 1024;
static constexpr size_t OFF_H2B    = OFF_H2A + 65536ull * 4;
static constexpr size_t CTL_END    = OFF_H2B + 65536ull * 4;
static constexpr size_t CTL_BYTES  = CTL_END - OFF_CTL;
static constexpr size_t OFF_SCAL   = CTL_END;                // 8-aligned
static constexpr size_t OFF_PART   = OFF_SCAL + 64;

__device__ __forceinline__ float mx3(float a, float b, float c){ return fmaxf(fmaxf(a,b),c); }
__device__ __forceinline__ float mn3(float a, float b, float c){ return fminf(fminf(a,b),c); }

__device__ __forceinline__ unsigned keyf(float x){
  unsigned b = __float_as_uint(x);
  return (b & 0x80000000u) ? ~b : (b | 0x80000000u);
}
__device__ __forceinline__ float keyinv(unsigned k){
  unsigned b = (k & 0x80000000u) ? (k ^ 0x80000000u) : ~k;
  return __uint_as_float(b);
}

// ---------- block-wide exclusive scan over 256 threads (4 waves, shfl) ----------
__device__ __forceinline__ unsigned excl_scan256(unsigned v, volatile unsigned* tmp, int t){
  int lane = t & 63, wv = t >> 6;
  unsigned inc = v;
  #pragma unroll
  for (int off = 1; off < 64; off <<= 1){
    unsigned u = __shfl_up(inc, off);
    if (lane >= off) inc += u;
  }
  if (lane == 63) tmp[wv] = inc;
  __syncthreads();
  unsigned wo = 0;
  #pragma unroll
  for (int w = 0; w < 4; w++) wo += (w < wv) ? tmp[w] : 0u;
  __syncthreads();
  return wo + inc - v;
}

// redundant per-block coarse scan: hi16 bins + in-bin ranks for RANK0, RANK0+1
__device__ __forceinline__ void coarse_rank(const unsigned* __restrict__ gh,
                                            const unsigned* __restrict__ under,
                                            unsigned* cres, volatile unsigned* stmp, int t){
  unsigned bins[16], loc = 0;
  #pragma unroll
  for (int i = 0; i < 16; i++){ bins[i] = gh[t*16 + i]; loc += bins[i]; }
  unsigned run = excl_scan256(loc, stmp, t) + under[0];
  #pragma unroll
  for (int i = 0; i < 16; i++){
    unsigned cc = bins[i];
    if (cc){
      if (RANK0 >= run && RANK0 - run < cc){ cres[0] = KEYLO + (unsigned)(t*16+i); cres[1] = RANK0 - run; }
      if (RANK0+1 >= run && RANK0+1 - run < cc){ cres[2] = KEYLO + (unsigned)(t*16+i); cres[3] = RANK0+1 - run; }
    }
    run += cc;
  }
  __syncthreads();
}

// find (bin, rank-within-bin) of rank r in a 256-bin histogram
__device__ __forceinline__ void rank256(const unsigned* __restrict__ h, unsigned r,
                                        unsigned* res2, volatile unsigned* stmp, int t){
  unsigned c = h[t];
  unsigned ex = excl_scan256(c, stmp, t);
  if (c && r >= ex && r - ex < c){ res2[0] = (unsigned)t; res2[1] = r - ex; }
  __syncthreads();
}

// 6-float window from one LDS row (R15 verbatim; compiles to b128 + 2 b32)
__device__ __forceinline__ void loadwin3q(const float* __restrict__ src, int rowbase,
                                          int gL, int gC, int gR, float w[6]){
  float4 vp = *reinterpret_cast<const float4*>(&src[rowbase + 4*gL]);
  float4 v  = *reinterpret_cast<const float4*>(&src[rowbase + 4*gC]);
  float4 vn = *reinterpret_cast<const float4*>(&src[rowbase + 4*gR]);
  w[0] = vp.w;
  w[1]=v.x; w[2]=v.y; w[3]=v.z; w[4]=v.w;
  w[5] = vn.x;
}

__device__ __forceinline__ void morph4(bool DIL,
    const float pr[6], const float cr[6], const float nr[6], float w[4]){
  #pragma unroll
  for (int i = 0; i < 4; i++){
    if (DIL){
      float Ah = mx3(cr[i],   cr[i+1], cr[i+2]);
      float Av = mx3(pr[i+1], cr[i+1], nr[i+1]);
      float Ad = mx3(pr[i],   cr[i+1], nr[i+2]);
      float Aa = mx3(pr[i+2], cr[i+1], nr[i]);
      float tm = mx3(pr[i], pr[i+1], pr[i+2]);
      float bm = mx3(nr[i], nr[i+1], nr[i+2]);
      float M9 = mx3(tm, Ah, bm);
      w[i] = fmaxf(M9, 1.0f + fminf(fminf(Ah,Av), fminf(Ad,Aa)));
    } else {
      float Bh = mn3(cr[i],   cr[i+1], cr[i+2]);
      float Bv = mn3(pr[i+1], cr[i+1], nr[i+1]);
      float Bd = mn3(pr[i],   cr[i+1], nr[i+2]);
      float Ba = mn3(pr[i+2], cr[i+1], nr[i]);
      float tm = mn3(pr[i], pr[i+1], pr[i+2]);
      float bm = mn3(nr[i], nr[i+1], nr[i+2]);
      float m9 = mn3(tm, Bh, bm);
      w[i] = fminf(m9, fmaxf(fmaxf(Bh,Bv), fmaxf(Bd,Ba)) - 1.0f);
    }
  }
}

// All 6 smoothing ops (D,E,E,D,D,E) on a 32x128 tile (R15 verbatim, ~51us)
__global__ __launch_bounds__(256)
void fused_morph_k(const float* __restrict__ in, float* __restrict__ out,
                   unsigned* __restrict__ gh, unsigned* __restrict__ under,
                   unsigned* __restrict__ over){
  __shared__ float lds[2][LR*LCP];
  const int tilec = blockIdx.x & 15;       // 16 col tiles
  const int tiler = blockIdx.x >> 4;       // 64 row tiles
  const int r0 = tiler*TH, c0 = tilec*TW;

  for (int idx = threadIdx.x; idx < LR*36; idx += 256){
    int lr = idx / 36, g = idx % 36;
    int gr = r0 - 6 + lr, gc = c0 - 8 + 4*g;
    float4 v = make_float4(0.f,0.f,0.f,0.f);
    if ((unsigned)gr < (unsigned)HH && (unsigned)gc < (unsigned)WW)
      v = *reinterpret_cast<const float4*>(in + (size_t)gr*WW + gc);
    *reinterpret_cast<float4*>(&lds[0][lr*LCP + 4*g]) = v;
  }
  __syncthreads();

  const int t = threadIdx.x;
  const int g = t % 36, s = t / 36;        // strip s covers compute rows [6s+1, 6s+7)
  const bool active = (t < 252);
  const int gL = g ? g - 1 : 0;
  const int gR = (g == 35) ? 35 : g + 1;
  const int gcBase = c0 - 8 + 4*g;
  const bool dilf[6] = {true,false,false,true,true,false};

  #pragma unroll 1
  for (int st = 0; st < 6; st++){
    const float* src = lds[st & 1];
    float*       dst = lds[(st & 1) ^ 1];
    if (active){
      const bool DIL = dilf[st];
      float r8[8][6];
      #pragma unroll
      for (int k = 0; k < 8; k++)
        loadwin3q(src, (6*s + k)*LCP, gL, g, gR, r8[k]);
      #pragma unroll
      for (int k = 0; k < 6; k++){
        float w[4];
        morph4(DIL, r8[k], r8[k+1], r8[k+2], w);
        int gr = r0 - 6 + 6*s + 1 + k;
        if ((unsigned)gr >= (unsigned)HH){
          w[0]=w[1]=w[2]=w[3]=0.f;
        } else {
          #pragma unroll
          for (int i = 0; i < 4; i++)
            if ((unsigned)(gcBase + i) >= (unsigned)WW) w[i] = 0.f;
        }
        *reinterpret_cast<float4*>(&dst[(6*s + 1 + k)*LCP + 4*g]) =
            make_float4(w[0],w[1],w[2],w[3]);
      }
    }
    __syncthreads();
  }
  unsigned* lh = reinterpret_cast<unsigned*>(&lds[1][0]);
  for (int i = threadIdx.x; i < NBINS; i += 256) lh[i] = 0;
  __syncthreads();

  unsigned uc = 0, oc = 0;
  for (int idx = threadIdx.x; idx < TH*(TW/4); idx += 256){
    int row = idx >> 5, gg = idx & 31;
    float4 v = *reinterpret_cast<const float4*>(&lds[0][(row+6)*LCP + 8 + 4*gg]);
    *reinterpret_cast<float4*>(out + (size_t)(r0+row)*WW + c0 + 4*gg) = v;
    float vv[4] = {v.x, v.y, v.z, v.w};
    #pragma unroll
    for (int i = 0; i < 4; i++){
      unsigned key = keyf(vv[i]);
      unsigned hi = key >> 16;
      if (hi >= KEYLO && hi < KEYHI_) atomicAdd(&lh[hi - KEYLO], 1u);
      else if (hi < KEYLO)            uc++;
      else                            oc++;
    }
  }
  __syncthreads();
  for (int i = threadIdx.x; i < NBINS; i += 256){
    unsigned c = lh[i];
    if (c) atomicAdd(&gh[i], c);
  }
  if (uc) atomicAdd(under, uc);
  if (oc) atomicAdd(over, oc);
}

// ONE fine pass with redundant per-block coarse scan (no fences; cross-kernel
// visibility from stream ordering): 256-bin mid hist + 65536-bin (mid,low) hist.
__global__ __launch_bounds__(256)
void fine2d_k(const float* __restrict__ x,
              const unsigned* __restrict__ coarse, const unsigned* __restrict__ under,
              unsigned* __restrict__ midA, unsigned* __restrict__ midB,
              unsigned* __restrict__ h2A, unsigned* __restrict__ h2B){
  __shared__ unsigned hA[256], hB[256];
  __shared__ unsigned stmp[4], cres[4];
  const int t = threadIdx.x;
  coarse_rank(coarse, under, cres, stmp, t);
  unsigned ha = cres[0], hb = cres[2];
  bool dup = (ha == hb);
  hA[t] = 0; hB[t] = 0;
  __syncthreads();
  const int nItems = NN/4;
  for (int it = blockIdx.x*blockDim.x + t; it < nItems; it += gridDim.x*blockDim.x){
    float4 v = reinterpret_cast<const float4*>(x)[it];
    float vv[4] = {v.x, v.y, v.z, v.w};
    #pragma unroll
    for (int j = 0; j < 4; j++){
      unsigned key = keyf(vv[j]);
      unsigned hi = key >> 16;
      if (hi == ha){ atomicAdd(&hA[(key>>8)&255], 1u); atomicAdd(&h2A[key & 0xFFFFu], 1u); }
      else if (hi == hb){ atomicAdd(&hB[(key>>8)&255], 1u); atomicAdd(&h2B[key & 0xFFFFu], 1u); }
    }
  }
  __syncthreads();
  if (hA[t]) atomicAdd(&midA[t], hA[t]);
  if (!dup && hB[t]) atomicAdd(&midB[t], hB[t]);
}

// load cols q-1..q+4 of `row` with zero padding (rows and cols)
__device__ __forceinline__ void load6(const float* __restrict__ p, int row, int q, float r[6]){
  if (row < 0 || row >= HH){
    r[0]=r[1]=r[2]=r[3]=r[4]=r[5]=0.f;
    return;
  }
  const float* rp = p + (size_t)row * WW;
  float4 cc = *reinterpret_cast<const float4*>(rp + q);
  r[0] = (q > 0) ? rp[q-1] : 0.f;
  r[1]=cc.x; r[2]=cc.y; r[3]=cc.z; r[4]=cc.w;
  r[5] = (q+4 < WW) ? rp[q+4] : 0.f;
}

// balloon: redundant per-block prologue resolves thr (coarse->mid->low), then
// xb = (origin > thr) ? 1+M9(x) : x, with f64 partial sums per block.
__global__ __launch_bounds__(256)
void balloon_k(const float* __restrict__ x, const float* __restrict__ orig,
               float* __restrict__ xb,
               const unsigned* __restrict__ coarse, const unsigned* __restrict__ under,
               const unsigned* __restrict__ midA, const unsigned* __restrict__ midB,
               const unsigned* __restrict__ h2A, const unsigned* __restrict__ h2B,
               double* __restrict__ part){
  __shared__ unsigned stmp[4], cres[4], mresA[2], mresB[2], lresA[2], lresB[2];
  __shared__ double red[4][3];
  const int t = threadIdx.x;

  coarse_rank(coarse, under, cres, stmp, t);
  unsigned ha = cres[0], rA = cres[1], hb = cres[2], rB = cres[3];
  bool dupHi = (ha == hb);
  rank256(midA, rA, mresA, stmp, t);
  rank256(dupHi ? midA : midB, rB, mresB, stmp, t);
  unsigned mA = mresA[0], rA2 = mresA[1], mB = mresB[0], rB2 = mresB[1];
  rank256(h2A + (size_t)mA*256, rA2, lresA, stmp, t);
  rank256((dupHi ? h2A : h2B) + (size_t)mB*256, rB2, lresB, stmp, t);
  unsigned ka = (ha << 16) | (mA << 8) | lresA[0];
  unsigned kb = (hb << 16) | (mB << 8) | lresB[0];
  double va = (double)keyinv(ka), vb = (double)keyinv(kb);
  const double FRAC = 0.4*(double)(NN-1) - (double)RANK0;   // np's gamma
  double thr = va + (vb - va) * FRAC;

  double s0 = 0.0, s1 = 0.0, s2 = 0.0;   // So, Sx, Sox
  const int nItems = NN/4;
  for (int it = blockIdx.x*blockDim.x + t; it < nItems; it += gridDim.x*blockDim.x){
    int i = it >> 9;
    int q = (it & 511) << 2;
    float a[6], b[6], c[6];
    load6(x, i-1, q, a);
    load6(x, i,   q, b);
    load6(x, i+1, q, c);
    float4 og = *reinterpret_cast<const float4*>(orig + (size_t)i*WW + q);
    float ov[4] = {og.x, og.y, og.z, og.w};
    float r[4];
    #pragma unroll
    for (int j = 0; j < 4; j++){
      float M9 = mx3(mx3(a[j],a[j+1],a[j+2]), mx3(b[j],b[j+1],b[j+2]), mx3(c[j],c[j+1],c[j+2]));
      float aux = 1.0f + M9;
      float nx = ((double)ov[j] > thr) ? aux : b[j+1];
      r[j] = nx;
      s0 += (double)ov[j];
      s1 += (double)nx;
      s2 += (double)ov[j] * (double)nx;
    }
    *reinterpret_cast<float4*>(xb + (size_t)i*WW + q) = make_float4(r[0],r[1],r[2],r[3]);
  }
  for (int off = 32; off > 0; off >>= 1){
    s0 += __shfl_down(s0, off);
    s1 += __shfl_down(s1, off);
    s2 += __shfl_down(s2, off);
  }
  int lane = t & 63, wv = t >> 6;
  if (lane == 0){ red[wv][0] = s0; red[wv][1] = s1; red[wv][2] = s2; }
  __syncthreads();
  if (t == 0){
    part[blockIdx.x*3+0] = red[0][0]+red[1][0]+red[2][0]+red[3][0];
    part[blockIdx.x*3+1] = red[0][1]+red[1][1]+red[2][1]+red[3][1];
    part[blockIdx.x*3+2] = red[0][2]+red[1][2]+red[2][2]+red[3][2];
  }
}

__global__ void c0c1_k(const double* __restrict__ part, Scal* __restrict__ sc){
  int t = threadIdx.x;
  double s0 = 0, s1 = 0, s2 = 0;
  for (int b = t; b < NPART; b += 256){
    s0 += part[b*3+0]; s1 += part[b*3+1]; s2 += part[b*3+2];
  }
  for (int off = 32; off > 0; off >>= 1){
    s0 += __shfl_down(s0, off);
    s1 += __shfl_down(s1, off);
    s2 += __shfl_down(s2, off);
  }
  __shared__ double red[4][3];
  int lane = t & 63, wv = t >> 6;
  if (lane == 0){ red[wv][0] = s0; red[wv][1] = s1; red[wv][2] = s2; }
  __syncthreads();
  if (t == 0){
    double So = red[0][0]+red[1][0]+red[2][0]+red[3][0];
    double Sx = red[0][1]+red[1][1]+red[2][1]+red[3][1];
    double Sox= red[0][2]+red[1][2]+red[2][2]+red[3][2];
    sc->c0 = (So - Sox) / ((double)NN - Sx + 1e-8);
    sc->c1 = Sox / (Sx + 1e-8);
  }
}

// final: elementwise Chan-Vese from origin + stored xb
__global__ __launch_bounds__(256)
void final_k(const float* __restrict__ orig, const float* __restrict__ xb,
             const Scal* __restrict__ sc, float* __restrict__ out){
  double c0 = sc->c0, c1 = sc->c1;
  const int nItems = NN/4;
  for (int it = blockIdx.x*blockDim.x + threadIdx.x; it < nItems; it += gridDim.x*blockDim.x){
    float4 og = reinterpret_cast<const float4*>(orig)[it];
    float4 xv = reinterpret_cast<const float4*>(xb)[it];
    float ov[4] = {og.x, og.y, og.z, og.w};
    float xx[4] = {xv.x, xv.y, xv.z, xv.w};
    float r[4];
    #pragma unroll
    for (int t = 0; t < 4; t++){
      double o = (double)ov[t];
      double d1 = o - c1, d0 = o - c0;
      double cv = d1*d1 - d0*d0;
      r[t] = (cv < 0.0) ? 1.0f : ((cv > 0.0) ? 0.0f : xx[t]);
    }
    reinterpret_cast<float4*>(out)[it] = make_float4(r[0],r[1],r[2],r[3]);
  }
}

extern "C" void kernel_launch(void* const* d_in, const int* in_sizes, int n_in,
                              void* d_out, int out_size, void* d_ws, size_t ws_size,
                              hipStream_t stream) {
  const float* input  = (const float*)d_in[0];
  const float* origin = (const float*)d_in[1];
  float* out = (float*)d_out;

  char* ws = (char*)d_ws;
  float*    bufA   = (float*)ws;
  unsigned* coarse = (unsigned*)(ws + OFF_COARSE);
  unsigned* under  = (unsigned*)(ws + OFF_UNDER);
  unsigned* over   = (unsigned*)(ws + OFF_OVER);
  unsigned* midA   = (unsigned*)(ws + OFF_MIDA);
  unsigned* midB   = (unsigned*)(ws + OFF_MIDB);
  unsigned* h2A    = (unsigned*)(ws + OFF_H2A);
  unsigned* h2B    = (unsigned*)(ws + OFF_H2B);
  Scal*     scal   = (Scal*)(ws + OFF_SCAL);
  double*   part   = (double*)(ws + OFF_PART);

  hipMemsetAsync(ws + OFF_CTL, 0, CTL_BYTES, stream);

  // morph -> fine2d(+coarse-scan prologue) -> balloon(+thr prologue) -> c0c1 -> final
  fused_morph_k<<<(HH/TH)*(WW/TW), 256, 0, stream>>>(input, out, coarse, under, over);
  fine2d_k<<<1024, 256, 0, stream>>>(out, coarse, under, midA, midB, h2A, h2B);
  balloon_k<<<NPART, 256, 0, stream>>>(out, origin, bufA, coarse, under,
                                       midA, midB, h2A, h2B, part);   // xb in bufA
  c0c1_k<<<1, 256, 0, stream>>>(part, scal);
  final_k<<<2048, 256, 0, stream>>>(origin, bufA, scal, out);
}